// Round 1
// 2001.181 us; speedup vs baseline: 1.0538x; 1.0538x over previous
//
#include <hip/hip_runtime.h>
#include <hip/hip_bf16.h>

#define SEQ 2048
#define BAT 2
#define HID 1024
#define NHD 16
#define HDM 64
#define LAY 12
#define MR (SEQ*BAT)   // 4096 rows, row = s*BAT + b

typedef short short8 __attribute__((ext_vector_type(8)));
typedef float f32x4 __attribute__((ext_vector_type(4)));

__device__ __forceinline__ unsigned short f2bf(float f){
  union { float f; unsigned u; } x; x.f = f;
  unsigned r = x.u + 0x7FFFu + ((x.u >> 16) & 1u);   // RNE
  return (unsigned short)(r >> 16);
}

__device__ __forceinline__ f32x4 mfma16(short8 a, short8 b, f32x4 c){
  return __builtin_amdgcn_mfma_f32_16x16x32_bf16(a, b, c, 0, 0, 0);
}

// async global->LDS, 16B per lane. LDS dest = wave-uniform base + lane*16.
__device__ __forceinline__ void glds16(const void* g, void* l){
  typedef const __attribute__((address_space(1))) unsigned int GQ;
  typedef __attribute__((address_space(3))) unsigned int LQ;
  __builtin_amdgcn_global_load_lds((GQ*)(unsigned long long)(uintptr_t)g,
                                   (LQ*)(unsigned int)(uintptr_t)l, 16, 0, 0);
}

// ---------------- fp32 -> bf16 convert (vectorized) ----------------
__global__ __launch_bounds__(256) void k_cvt(const float* __restrict__ in,
                                             unsigned short* __restrict__ out){
  int i = (blockIdx.x*256 + threadIdx.x)*4;
  float4 v = *(const float4*)(in + i);
  ushort4 o; o.x=f2bf(v.x); o.y=f2bf(v.y); o.z=f2bf(v.z); o.w=f2bf(v.w);
  *(ushort4*)(out + i) = o;
}

// ------- W (K x N, fp32) -> Wt (N x K, bf16), 64x64 tiles, XOR-swizzled LDS -------
__global__ __launch_bounds__(256) void k_transpose(const float* __restrict__ W0, const float* __restrict__ W1,
                                                   const float* __restrict__ W2, const float* __restrict__ W3,
                                                   unsigned short* __restrict__ wt){
  int mi = blockIdx.z;
  const float* W = (mi==0)?W0:(mi==1)?W1:(mi==2)?W2:W3;
  unsigned short* out = wt + (size_t)mi*HID*HID;
  int nb = blockIdx.x*64, kb = blockIdx.y*64;
  int tid = threadIdx.x;
  __shared__ unsigned short T[64][64];
  #pragma unroll
  for (int i=0;i<4;i++){
    int li = tid + i*256;
    int kr = li >> 4, ns = li & 15;
    float4 v = *(const float4*)(W + (size_t)(kb+kr)*HID + nb + ns*4);
    int n0 = ns*4;
    T[kr][(n0+0) ^ kr] = f2bf(v.x);
    T[kr][(n0+1) ^ kr] = f2bf(v.y);
    T[kr][(n0+2) ^ kr] = f2bf(v.z);
    T[kr][(n0+3) ^ kr] = f2bf(v.w);
  }
  __syncthreads();
  #pragma unroll
  for (int i=0;i<2;i++){
    int li = tid + i*256;
    int nr = li >> 3, ks = li & 7;
    unsigned short t8[8];
    #pragma unroll
    for (int j=0;j<8;j++){ int k = ks*8+j; t8[j] = T[k][nr ^ k]; }
    *(uint4*)(out + (size_t)(nb+nr)*HID + kb + ks*8) = *(uint4*)t8;
  }
}

// ---------------- 128x128-tile bf16 GEMM with global_load_lds staging ----------------
// LDS raw pitch-64, XOR swizzle baked into per-lane GLOBAL source chunk:
// As[row][c] holds global chunk c ^ (row&7); frag read chunk = want ^ (lr&7).
template<int OUT_BF16>
__global__ __launch_bounds__(256) void k_gemm(const unsigned short* __restrict__ A,
      const unsigned short* __restrict__ Bt0, const unsigned short* __restrict__ Bt1, const unsigned short* __restrict__ Bt2,
      const float* __restrict__ bias0, const float* __restrict__ bias1, const float* __restrict__ bias2,
      void* __restrict__ o0, void* __restrict__ o1, void* __restrict__ o2){
  const int z = blockIdx.z;
  const unsigned short* Bt = (z==0)?Bt0:(z==1)?Bt1:Bt2;
  const float* bias = (z==0)?bias0:(z==1)?bias1:bias2;
  void* outp = (z==0)?o0:(z==1)?o1:o2;

  const int n0 = blockIdx.x * 128;
  const int m0 = blockIdx.y * 128;
  const int tid = threadIdx.x;
  const int lane = tid & 63;
  const int w = tid >> 6;
  const int wm = w >> 1, wn = w & 1;
  const int lr = lane & 15, lq = lane >> 4;
  const int lsw = lr & 7;
  const int kr = lane >> 3, kc = lane & 7;
  const int gch = kc ^ kr;              // swizzled source chunk

  __shared__ unsigned short As[128][64];
  __shared__ unsigned short Bs[128][64];

  f32x4 zero = {0.f,0.f,0.f,0.f};
  f32x4 acc[4][4];
  #pragma unroll
  for (int i=0;i<4;i++)
    #pragma unroll
    for (int j=0;j<4;j++) acc[i][j] = zero;

  for (int kt = 0; kt < HID/64; ++kt){
    __syncthreads();
    #pragma unroll
    for (int i=0;i<4;i++){
      int r = i*32 + w*8;
      glds16(A  + (size_t)(m0+r+kr)*HID + kt*64 + gch*8, &As[r][0]);
      glds16(Bt + (size_t)(n0+r+kr)*HID + kt*64 + gch*8, &Bs[r][0]);
    }
    __syncthreads();
    #pragma unroll
    for (int kk=0; kk<2; ++kk){
      short8 af[4], bf[4];
      #pragma unroll
      for (int mi=0;mi<4;mi++) af[mi] = *(const short8*)(&As[wm*64+mi*16+lr][((kk*4+lq)^lsw)*8]);
      #pragma unroll
      for (int ni=0;ni<4;ni++) bf[ni] = *(const short8*)(&Bs[wn*64+ni*16+lr][((kk*4+lq)^lsw)*8]);
      #pragma unroll
      for (int mi=0;mi<4;mi++)
        #pragma unroll
        for (int ni=0;ni<4;ni++)
          acc[mi][ni] = mfma16(af[mi], bf[ni], acc[mi][ni]);
    }
  }
  #pragma unroll
  for (int ni=0;ni<4;ni++){
    int n = n0 + wn*64 + ni*16 + lr;
    float bv = bias[n];
    #pragma unroll
    for (int mi=0;mi<4;mi++){
      int mbase = m0 + wm*64 + mi*16 + lq*4;
      #pragma unroll
      for (int r=0;r<4;r++){
        float val = acc[mi][ni][r] + bv;
        if (OUT_BF16) ((unsigned short*)outp)[(size_t)(mbase+r)*HID + n] = f2bf(val);
        else          ((float*)outp)[(size_t)(mbase+r)*HID + n] = val;
      }
    }
  }
}

// ---------------- flash attention v4 ----------------
// 128 q-rows/block, 8 waves x 16 q-rows each (512 thr), 64-key tiles, dbuf K/V,
// 1 barrier/iter. LDS 48KB, grid 512 = 2 blocks/CU -> 16 waves/CU (2x v3).
// K staged via global_load_lds (swizzle in source address).
// Row-sums via MFMA ones-trick. setprio(1) around MFMA clusters (T5).
__global__ __launch_bounds__(512) void k_attn(const unsigned short* __restrict__ qb,
                                              const unsigned short* __restrict__ kb,
                                              const unsigned short* __restrict__ vb,
                                              const float* __restrict__ mask,
                                              unsigned short* __restrict__ cb){
  const int qblk = blockIdx.x;   // 0..15
  const int h = blockIdx.y;      // 0..15
  const int b = blockIdx.z;      // 0..1
  const int tid = threadIdx.x;
  const int w = tid >> 6;        // 0..7
  const int lane = tid & 63;
  const int lr = lane & 15, lq = lane >> 4;
  const int lsw = lr & 7;
  const int col0 = h * HDM;
  const int q0 = qblk*128 + w*16;

  __shared__ unsigned short Ks[2][64][64];   // [buf][key][hd], chunk^=(key&7)
  __shared__ unsigned short Vs[2][64][64];   // [buf][hd][kappa], chunk^=(hd&7)
  __shared__ unsigned short Pb[8][16][64];   // [wave][qrow][kappa], chunk^=(qrow&7)

  short8 qf[2];
  {
    const unsigned short* qrow = qb + ((size_t)(q0 + lr)*BAT + b)*HID + col0;
    qf[0] = *(const short8*)(qrow + lq*8);
    qf[1] = *(const short8*)(qrow + 32 + lq*8);
  }

  const int kr = lane >> 3, kc = lane & 7;
  const int gch = kc ^ kr;
  const int kappa = (lane & 15)*4 + (lane >> 4);

  f32x4 zero = {0.f,0.f,0.f,0.f};
  f32x4 cacc[4], lacc = zero;
  #pragma unroll
  for (int i=0;i<4;i++) cacc[i] = zero;
  short8 ones;
  #pragma unroll
  for (int j=0;j<8;j++) ones[j] = (short)0x3F80;  // bf16 1.0
  const float cs1 = 0.18033688011112042f;    // 0.125 * log2(e)
  const float l2e = 1.4426950408889634f;

  // prologue: stage tile 0 into buffer 0 (each wave: 8 K-rows, 8 V-hd-rows)
  glds16(kb + ((size_t)(w*8+kr)*BAT + b)*HID + col0 + gch*8, &Ks[0][w*8][0]);
  uint4 vreg = *(const uint4*)(vb + ((size_t)lane*BAT + b)*HID + col0 + w*8);
  {
    union { uint4 v; unsigned short s8[8]; } t; t.v = vreg;
    #pragma unroll
    for (int j=0;j<8;j++)
      Vs[0][w*8+j][(((kappa>>3)^j)<<3) | (kappa&7)] = t.s8[j];
  }
  __syncthreads();

  for (int kt=0; kt<SEQ/64; ++kt){
    const int cur = kt & 1;
    const int key0 = kt*64;
    // mask first (oldest vmcnt)
    float mkl[4];
    #pragma unroll
    for (int t=0;t<4;t++) mkl[t] = mask[b*SEQ + key0 + t*16 + lr];
    // prefetch next tile: K async into Ks[nxt], V into regs
    if (kt+1 < SEQ/64){
      const int nk0 = key0 + 64;
      const int nxt = cur^1;
      glds16(kb + ((size_t)(nk0+w*8+kr)*BAT + b)*HID + col0 + gch*8, &Ks[nxt][w*8][0]);
      vreg = *(const uint4*)(vb + ((size_t)(nk0+lane)*BAT + b)*HID + col0 + w*8);
    }
    #pragma unroll
    for (int t=0;t<4;t++) mkl[t] *= l2e;
    // scores
    f32x4 s[4];
    __builtin_amdgcn_s_setprio(1);
    #pragma unroll
    for (int t=0;t<4;t++){
      short8 kf0 = *(const short8*)(&Ks[cur][t*16+lr][(lq^lsw)*8]);
      short8 kf1 = *(const short8*)(&Ks[cur][t*16+lr][((4+lq)^lsw)*8]);
      f32x4 a0 = mfma16(qf[0], kf0, zero);
      s[t] = mfma16(qf[1], kf1, a0);
    }
    __builtin_amdgcn_s_setprio(0);
    // streaming softmax (no max-shift, no reductions) + swizzled P store
    #pragma unroll
    for (int r=0;r<4;r++){
      float p0 = exp2f(fmaf(s[0][r], cs1, mkl[0]));
      float p1 = exp2f(fmaf(s[1][r], cs1, mkl[1]));
      float p2 = exp2f(fmaf(s[2][r], cs1, mkl[2]));
      float p3 = exp2f(fmaf(s[3][r], cs1, mkl[3]));
      union { __hip_bfloat162 h; unsigned u; } c01, c23;
      c01.h = __float22bfloat162_rn(make_float2(p0,p1));
      c23.h = __float22bfloat162_rn(make_float2(p2,p3));
      uint2 pk; pk.x = c01.u; pk.y = c23.u;
      int qrow = lq*4+r;
      int chp = (lr>>1) ^ (qrow&7);
      *(uint2*)(&Pb[w][qrow][chp*8 + (lr&1)*4]) = pk;
    }
    __builtin_amdgcn_s_waitcnt(0xc07f);  // lgkmcnt(0): own-wave Pb writes visible
    // PV + row-sum MFMA
    __builtin_amdgcn_s_setprio(1);
    #pragma unroll
    for (int kk=0;kk<2;kk++){
      short8 vf[4];
      #pragma unroll
      for (int ni=0;ni<4;ni++) vf[ni] = *(const short8*)(&Vs[cur][ni*16+lr][((kk*4+lq)^lsw)*8]);
      short8 pf = *(const short8*)(&Pb[w][lr][((kk*4+lq)^lsw)*8]);
      lacc = mfma16(pf, ones, lacc);
      #pragma unroll
      for (int ni=0;ni<4;ni++) cacc[ni] = mfma16(pf, vf[ni], cacc[ni]);
    }
    __builtin_amdgcn_s_setprio(0);
    // store prefetched V, single barrier
    if (kt+1 < SEQ/64){
      const int nxt = cur^1;
      union { uint4 v; unsigned short s8[8]; } t; t.v = vreg;
      #pragma unroll
      for (int j=0;j<8;j++)
        Vs[nxt][w*8+j][(((kappa>>3)^j)<<3) | (kappa&7)] = t.s8[j];
      __syncthreads();
    }
  }
  // epilogue
  #pragma unroll
  for (int r=0;r<4;r++){
    float inv = 1.0f / lacc[r];
    int sx = q0 + lq*4 + r;
    #pragma unroll
    for (int ni=0;ni<4;ni++)
      cb[((size_t)sx*BAT + b)*HID + col0 + ni*16 + lr] = f2bf(cacc[ni][r]*inv);
  }
}

// ---------------- residual + LayerNorm (two-pass, fp32) ----------------
__global__ __launch_bounds__(256) void k_ln(const float* __restrict__ dense, const float* __restrict__ resid,
                                            const float* __restrict__ gamma, const float* __restrict__ beta,
                                            float* __restrict__ xf, unsigned short* __restrict__ xb,
                                            float* __restrict__ fout){
  const int row = blockIdx.x, tid = threadIdx.x;
  const size_t base = (size_t)row*HID + tid*4;
  float4 dv = *(const float4*)(dense + base);
  float4 rv = *(const float4*)(resid + base);
  float v0 = dv.x+rv.x, v1 = dv.y+rv.y, v2 = dv.z+rv.z, v3 = dv.w+rv.w;
  float s = v0+v1+v2+v3;
  #pragma unroll
  for (int off=32; off>0; off>>=1) s += __shfl_xor(s, off);
  __shared__ float sm[4];
  __shared__ float st[2];
  int w = tid>>6, lane = tid&63;
  if (lane==0) sm[w] = s;
  __syncthreads();
  if (tid==0) st[0] = (sm[0]+sm[1]+sm[2]+sm[3]) * (1.0f/HID);
  __syncthreads();
  float mean = st[0];
  float c0=v0-mean, c1=v1-mean, c2=v2-mean, c3=v3-mean;
  float q = c0*c0+c1*c1+c2*c2+c3*c3;
  #pragma unroll
  for (int off=32; off>0; off>>=1) q += __shfl_xor(q, off);
  if (lane==0) sm[w] = q;
  __syncthreads();
  if (tid==0) st[1] = (sm[0]+sm[1]+sm[2]+sm[3]) * (1.0f/HID);
  __syncthreads();
  float rstd = rsqrtf(st[1] + 1e-12f);
  float4 g  = *(const float4*)(gamma + tid*4);
  float4 be = *(const float4*)(beta + tid*4);
  float y0 = c0*rstd*g.x + be.x;
  float y1 = c1*rstd*g.y + be.y;
  float y2 = c2*rstd*g.z + be.z;
  float y3 = c3*rstd*g.w + be.w;
  if (fout){
    float4 o = {y0,y1,y2,y3};
    *(float4*)(fout + base) = o;
  } else {
    float4 o = {y0,y1,y2,y3};
    *(float4*)(xf + base) = o;
    ushort4 ob; ob.x=f2bf(y0); ob.y=f2bf(y1); ob.z=f2bf(y2); ob.w=f2bf(y3);
    *(ushort4*)(xb + base) = ob;
  }
}

extern "C" void kernel_launch(void* const* d_in, const int* in_sizes, int n_in,
                              void* d_out, int out_size, void* d_ws, size_t ws_size,
                              hipStream_t stream){
  const float* input = (const float*)d_in[0];
  const float* mask  = (const float*)d_in[1];
  const float* Wq = (const float*)d_in[2];
  const float* bq = (const float*)d_in[3];
  const float* Wk = (const float*)d_in[4];
  const float* bk = (const float*)d_in[5];
  const float* Wv = (const float*)d_in[6];
  const float* bv = (const float*)d_in[7];
  const float* Wo = (const float*)d_in[8];
  const float* bo = (const float*)d_in[9];
  const float* gamma = (const float*)d_in[10];
  const float* beta  = (const float*)d_in[11];
  float* out = (float*)d_out;

  char* p = (char*)d_ws;
  unsigned short* xb = (unsigned short*)p; p += (size_t)MR*HID*2;
  unsigned short* qb = (unsigned short*)p; p += (size_t)MR*HID*2;
  unsigned short* kb = (unsigned short*)p; p += (size_t)MR*HID*2;
  unsigned short* vb = (unsigned short*)p; p += (size_t)MR*HID*2;
  unsigned short* cb = (unsigned short*)p; p += (size_t)MR*HID*2;
  unsigned short* wt = (unsigned short*)p; p += (size_t)4*HID*HID*2;
  float* dense = (float*)p; p += (size_t)MR*HID*4;
  float* xf    = (float*)p; p += (size_t)MR*HID*4;

  const size_t WW = (size_t)HID*HID;

  k_cvt<<<(MR*HID)/1024, 256, 0, stream>>>(input, xb);

  for (int l=0; l<LAY; ++l){
    k_transpose<<<dim3(16,16,4), 256, 0, stream>>>(Wq+l*WW, Wk+l*WW, Wv+l*WW, Wo+l*WW, wt);
    k_gemm<1><<<dim3(8,32,3), 256, 0, stream>>>(xb, wt, wt+WW, wt+2*WW,
                                                bq+l*HID, bk+l*HID, bv+l*HID,
                                                qb, kb, vb);
    k_attn<<<dim3(16,16,2), 512, 0, stream>>>(qb, kb, vb, mask, cb);
    k_gemm<0><<<dim3(8,32,1), 256, 0, stream>>>(cb, wt+3*WW, wt+3*WW, wt+3*WW,
                                                bo+l*HID, bo+l*HID, bo+l*HID,
                                                dense, dense, dense);
    const float* resid = (l==0) ? input : xf;
    const bool last = (l == LAY-1);
    k_ln<<<MR, 256, 0, stream>>>(dense, resid, gamma+l*HID, beta+l*HID,
                                 last ? (float*)nullptr : xf,
                                 last ? (unsigned short*)nullptr : xb,
                                 last ? out : (float*)nullptr);
  }
}